// Round 3
// baseline (254.236 us; speedup 1.0000x reference)
//
#include <hip/hip_runtime.h>

// Gated delta-rule recurrent cell, single step. B=128, H=16, Dk=Dv=128.
//
// Round-3: persistent pipelined stream. ONE WAVE owns one full (b,h) 128x128
// state tile, processed as 4 column-slices of 32 with REGISTER DOUBLE
// BUFFERING: prefetch slice s+1 (16 dwordx4/lane) -> compute+store slice s.
// Steady state each wave has reads AND writes concurrently in flight for its
// whole lifetime (copy-kernel profile), unlike rounds 0-2 whose one-shot
// load-burst/drain/store-burst structure pinned at 2.5-2.7 TB/s.
// Lane layout per slice: vgrp=lane&7 (8 f4 = 32 cols), kgrp=lane>>3 (8 row
// groups x 16 rows). k-reduction = 3-round __shfl_xor butterfly (8/16/32).
// k,q register-resident across slices; bh block-uniform (64-thr blocks) so
// g/beta/k/q go through scalar/L1 paths.
// out[v] = decay*Bq[v] + (k.q)*delta[v]  (algebraic identity, single pass)

#define DK 128
#define DV 128
typedef float f4 __attribute__((ext_vector_type(4)));

__global__ __launch_bounds__(64) void s1_cell_kernel(
    const float* __restrict__ q,
    const float* __restrict__ k,
    const float* __restrict__ v,
    const float* __restrict__ g,
    const float* __restrict__ beta,
    const float* __restrict__ S,
    float* __restrict__ out,      // full d_out
    int BH)
{
    const int bh   = blockIdx.x;
    const int lane = threadIdx.x;        // 0..63
    const int vgrp = lane & 7;           // f4-column within 32-col slice
    const int kgrp = lane >> 3;          // 8 row groups x 16 rows
    const int row0 = kgrp * 16;
    const int c0   = vgrp * 4;

    const size_t stile = (size_t)bh * (DK * DV);
    const float* __restrict__ Sb = S + stile;
    float* __restrict__ oS = out + (size_t)BH * DV + stile;
    float* __restrict__ oO = out + (size_t)bh * DV;

    // per-lane k,q rows (row0 .. row0+15), register-resident for all slices
    f4 kt[4], qt[4];
    #pragma unroll
    for (int j = 0; j < 4; ++j) {
        kt[j] = *(const f4*)(k + bh * DK + row0 + 4 * j);
        qt[j] = *(const f4*)(q + bh * DK + row0 + 4 * j);
    }
    const float decay = expf(g[bh]);
    const float bta   = beta[bh];

    // k.q once: per-lane partial over its 16 rows, butterfly over kgrp axis
    float kq = 0.f;
    #pragma unroll
    for (int j = 0; j < 4; ++j)
        kq += kt[j].x*qt[j].x + kt[j].y*qt[j].y + kt[j].z*qt[j].z + kt[j].w*qt[j].w;
    #pragma unroll
    for (int m = 8; m <= 32; m <<= 1)
        kq += __shfl_xor(kq, m, 64);

    f4 sA[16], sB[16];

    // prologue: load slice 0
    #pragma unroll
    for (int i = 0; i < 16; ++i)
        sA[i] = *(const f4*)(Sb + (size_t)(row0 + i) * DV + c0);

    // One pipeline step: prefetch slice SL+1 into NXT (if PF), then
    // compute + store slice SL from CUR. Buffers alternate by macro name so
    // all register indices are compile-time (no scratch).
#define STEP(CUR, NXT, SL, PF)                                              \
    {                                                                       \
        const int colf = (SL) * 32 + c0;                                    \
        if (PF) {                                                           \
            _Pragma("unroll")                                               \
            for (int i = 0; i < 16; ++i)                                    \
                NXT[i] = *(const f4*)(Sb + (size_t)(row0 + i) * DV          \
                                      + colf + 32);                         \
        }                                                                   \
        f4 a = {0.f,0.f,0.f,0.f}, b = {0.f,0.f,0.f,0.f};                    \
        _Pragma("unroll")                                                   \
        for (int j = 0; j < 4; ++j) {                                       \
            a += CUR[4*j+0] * kt[j].x;  b += CUR[4*j+0] * qt[j].x;          \
            a += CUR[4*j+1] * kt[j].y;  b += CUR[4*j+1] * qt[j].y;          \
            a += CUR[4*j+2] * kt[j].z;  b += CUR[4*j+2] * qt[j].z;          \
            a += CUR[4*j+3] * kt[j].w;  b += CUR[4*j+3] * qt[j].w;          \
        }                                                                   \
        _Pragma("unroll")                                                   \
        for (int m = 8; m <= 32; m <<= 1) {                                 \
            a.x += __shfl_xor(a.x, m, 64); a.y += __shfl_xor(a.y, m, 64);   \
            a.z += __shfl_xor(a.z, m, 64); a.w += __shfl_xor(a.w, m, 64);   \
            b.x += __shfl_xor(b.x, m, 64); b.y += __shfl_xor(b.y, m, 64);   \
            b.z += __shfl_xor(b.z, m, 64); b.w += __shfl_xor(b.w, m, 64);   \
        }                                                                   \
        const f4 vv  = *(const f4*)(v + bh * DV + colf);                    \
        const f4 dlt = (vv - decay * a) * bta;                              \
        if (kgrp == 0)                                                      \
            __builtin_nontemporal_store(decay * b + kq * dlt,               \
                                        (f4*)(oO + colf));                  \
        _Pragma("unroll")                                                   \
        for (int i = 0; i < 16; ++i) {                                      \
            const float kv = ((const float*)kt)[i];                         \
            __builtin_nontemporal_store(decay * CUR[i] + kv * dlt,          \
                (f4*)(oS + (size_t)(row0 + i) * DV + colf));                \
        }                                                                   \
    }

    STEP(sA, sB, 0, 1);
    STEP(sB, sA, 1, 1);
    STEP(sA, sB, 2, 1);
    STEP(sB, sA, 3, 0);
#undef STEP
}

extern "C" void kernel_launch(void* const* d_in, const int* in_sizes, int n_in,
                              void* d_out, int out_size, void* d_ws, size_t ws_size,
                              hipStream_t stream) {
    const float* q    = (const float*)d_in[0];
    const float* k    = (const float*)d_in[1];
    const float* v    = (const float*)d_in[2];
    const float* g    = (const float*)d_in[3];
    const float* beta = (const float*)d_in[4];
    const float* S    = (const float*)d_in[5];
    float* out = (float*)d_out;

    const int BH = in_sizes[3];   // g has B*H elements = 2048

    // one 64-thread block (one wave) per (b,h) tile
    s1_cell_kernel<<<BH, 64, 0, stream>>>(q, k, v, g, beta, S, out, BH);
}

// Round 4
// 249.350 us; speedup vs baseline: 1.0196x; 1.0196x over previous
//
#include <hip/hip_runtime.h>

// Gated delta-rule recurrent cell, single step. B=128, H=16, Dk=Dv=128.
//
// Round-4: CONTIGUOUS WAVE ACCESS. Previous rounds all issued wave loads as
// 8 scattered 128-B segments (lanes split across k-row groups) and pinned at
// 2.4-2.7 TB/s regardless of occupancy/pipelining. This version makes every
// S load/store ONE contiguous 1024-B segment per wave instruction (the
// pattern of every >6 TB/s kernel on this chip).
//
// Block = one (b,h) tile, 4 waves. Wave w owns rows [32w, 32w+32).
// Lane: half=lane>>5 (row parity), c0=(lane&31)*4 (column group).
// Load i: row pair (32w+2i+half), cols c0 -> lanes 0..63 cover exactly
// rows 2i,2i+1 full 512B each = contiguous 1KB.
// Reduction over k: per-lane FMA (16 rows) -> shfl_xor(32) parity merge ->
// 4-wave partial merge via 4KB LDS, ONE barrier.
// out[v] = decay*Bq[v] + (k.q)*delta[v]  (single pass identity)

#define DK 128
#define DV 128
typedef float f4 __attribute__((ext_vector_type(4)));

__global__ __launch_bounds__(256) void s1_cell_kernel(
    const float* __restrict__ q,
    const float* __restrict__ k,
    const float* __restrict__ v,
    const float* __restrict__ g,
    const float* __restrict__ beta,
    const float* __restrict__ S,
    float* __restrict__ out,      // full d_out
    int BH)
{
    const int bh   = blockIdx.x;
    const int w    = threadIdx.x >> 6;     // wave 0..3 -> rows [32w,32w+32)
    const int lane = threadIdx.x & 63;
    const int half = lane >> 5;            // row parity within pair
    const int c0   = (lane & 31) * 4;      // column (float idx) 0..124

    __shared__ float apart[4][DV];         // per-wave partial S^T k
    __shared__ float bpart[4][DV];         // per-wave partial S^T q
    __shared__ float skq[4];

    const size_t stile = (size_t)bh * (DK * DV);
    const float* __restrict__ Sb = S + stile;
    float* __restrict__ oS = out + (size_t)BH * DV + stile;

    const int r0 = 32 * w + half;          // lane's base row

    // --- S strip: 16 contiguous 1KB wave loads (rows r0+2i, cols c0) ---
    f4 s[16];
    #pragma unroll
    for (int i = 0; i < 16; ++i)
        s[i] = *(const f4*)(Sb + (size_t)(r0 + 2 * i) * DV + c0);

    // k,q for this lane's 16 rows (two L1-broadcast segments per instr, tiny)
    float kv[16], qv[16];
    #pragma unroll
    for (int i = 0; i < 16; ++i) {
        kv[i] = k[bh * DK + r0 + 2 * i];
        qv[i] = q[bh * DK + r0 + 2 * i];
    }

    const float decay = expf(g[bh]);
    const float bta   = beta[bh];

    // --- per-lane partials over 16 rows ---
    f4 a = {0.f, 0.f, 0.f, 0.f};
    f4 b = {0.f, 0.f, 0.f, 0.f};
    float kqp = 0.f;
    #pragma unroll
    for (int i = 0; i < 16; ++i) {
        a   += s[i] * kv[i];
        b   += s[i] * qv[i];
        kqp += kv[i] * qv[i];
    }

    // merge row parities (lane ^ 32)
    a.x += __shfl_xor(a.x, 32, 64);  a.y += __shfl_xor(a.y, 32, 64);
    a.z += __shfl_xor(a.z, 32, 64);  a.w += __shfl_xor(a.w, 32, 64);
    b.x += __shfl_xor(b.x, 32, 64);  b.y += __shfl_xor(b.y, 32, 64);
    b.z += __shfl_xor(b.z, 32, 64);  b.w += __shfl_xor(b.w, 32, 64);
    kqp += __shfl_xor(kqp, 32, 64);

    if (lane < 32) {
        *(f4*)&apart[w][c0] = a;
        *(f4*)&bpart[w][c0] = b;
        if (lane == 0) skq[w] = kqp;
    }
    __syncthreads();

    // --- finish cross-wave reduction (broadcast LDS reads, conflict-free) ---
    f4 A  = *(const f4*)&apart[0][c0];
    f4 Bq = *(const f4*)&bpart[0][c0];
    #pragma unroll
    for (int j = 1; j < 4; ++j) {
        A  += *(const f4*)&apart[j][c0];
        Bq += *(const f4*)&bpart[j][c0];
    }
    const float kq = skq[0] + skq[1] + skq[2] + skq[3];

    const f4 vv  = *(const f4*)(v + bh * DV + c0);
    const f4 dlt = (vv - decay * A) * bta;

    if (w == 0 && lane < 32)
        *(f4*)(out + (size_t)bh * DV + c0) = decay * Bq + kq * dlt;

    // --- rewrite state: 16 contiguous 1KB wave stores ---
    #pragma unroll
    for (int i = 0; i < 16; ++i) {
        const f4 wr = decay * s[i] + kv[i] * dlt;
        __builtin_nontemporal_store(wr,
            (f4*)(oS + (size_t)(r0 + 2 * i) * DV + c0));
    }
}

extern "C" void kernel_launch(void* const* d_in, const int* in_sizes, int n_in,
                              void* d_out, int out_size, void* d_ws, size_t ws_size,
                              hipStream_t stream) {
    const float* q    = (const float*)d_in[0];
    const float* k    = (const float*)d_in[1];
    const float* v    = (const float*)d_in[2];
    const float* g    = (const float*)d_in[3];
    const float* beta = (const float*)d_in[4];
    const float* S    = (const float*)d_in[5];
    float* out = (float*)d_out;

    const int BH = in_sizes[3];   // g has B*H elements = 2048

    s1_cell_kernel<<<BH, 256, 0, stream>>>(q, k, v, g, beta, S, out, BH);
}